// Round 1
// baseline (699.714 us; speedup 1.0000x reference)
//
#include <hip/hip_runtime.h>
#include <stdint.h>

#define BATCH 8
#define NLEAF 64
#define VOCAB 128000
#define ROW (NLEAF * VOCAB)        // 8,192,000
#define CHUNK 4096
#define NCHUNK (ROW / CHUNK)       // 2000 (exact)
#define TOPK 64

// ---------------------------------------------------------------------------
// Kernel 1: per-chunk max of product. One block = one 4096-elem chunk.
// A chunk spans at most 2 leaves (CHUNK < VOCAB); VOCAB%4==0 and all float4
// loads are 4-aligned in the row, so a float4 never straddles a leaf boundary.
// ---------------------------------------------------------------------------
__global__ __launch_bounds__(256) void k_chunkmax(
    const float* __restrict__ sp, const float* __restrict__ pp,
    float* __restrict__ cmax)
{
    int c   = blockIdx.x;            // 0 .. BATCH*NCHUNK-1
    int row = c / NCHUNK;
    int cr  = c - row * NCHUNK;
    long base = (long)row * ROW + (long)cr * CHUNK;
    int fr    = cr * CHUNK;          // row-local flat base
    int leaf0 = fr / VOCAB;
    int bnd   = (leaf0 + 1) * VOCAB; // row-local boundary (multiple of 4)
    float p0  = pp[row * NLEAF + leaf0];
    float p1  = (leaf0 + 1 < NLEAF) ? pp[row * NLEAF + leaf0 + 1] : 0.f;

    int t = threadIdx.x;
    const float4* sp4 = (const float4*)(sp + base);
    float m = 0.f;                   // products are >= 0
#pragma unroll
    for (int i = 0; i < 4; ++i) {
        int e4 = t + i * 256;        // float4 index within chunk
        float4 v = sp4[e4];
        float p = ((fr + e4 * 4) < bnd) ? p0 : p1;
        m = fmaxf(m, fmaxf(fmaxf(v.x * p, v.y * p), fmaxf(v.z * p, v.w * p)));
    }
    // wave64 shuffle reduce, then 4-wave LDS reduce
    for (int off = 32; off; off >>= 1) m = fmaxf(m, __shfl_down(m, off, 64));
    __shared__ float s[4];
    if ((t & 63) == 0) s[t >> 6] = m;
    __syncthreads();
    if (t == 0) cmax[c] = fmaxf(fmaxf(s[0], s[1]), fmaxf(s[2], s[3]));
}

// ---------------------------------------------------------------------------
// Kernel 2: per row, find the 64th-largest chunk max -> threshold.
// Also zeroes the candidate counter (ws is poisoned 0xAA each launch).
// ---------------------------------------------------------------------------
__global__ __launch_bounds__(256) void k_threshold(
    const float* __restrict__ cmax, float* __restrict__ thr,
    int* __restrict__ cnt)
{
    int row = blockIdx.x;
    __shared__ float vals[NCHUNK];
    __shared__ float smax[256];
    __shared__ int   spos[256];
    int t = threadIdx.x;
    for (int i = t; i < NCHUNK; i += 256) vals[i] = cmax[row * NCHUNK + i];
    if (t == 0) cnt[row] = 0;
    __syncthreads();

    float tlocal = 0.f;
    for (int it = 0; it < TOPK; ++it) {
        float lm = -1.f; int lp = -1;
        for (int i = t; i < NCHUNK; i += 256) {
            float v = vals[i];
            if (v > lm) { lm = v; lp = i; }
        }
        smax[t] = lm; spos[t] = lp;
        __syncthreads();
        for (int off = 128; off; off >>= 1) {
            if (t < off && smax[t + off] > smax[t]) {
                smax[t] = smax[t + off]; spos[t] = spos[t + off];
            }
            __syncthreads();
        }
        if (t == 0) { tlocal = smax[0]; vals[spos[0]] = -1.f; }
        __syncthreads();
    }
    if (t == 0) thr[row] = tlocal;
}

// ---------------------------------------------------------------------------
// Kernel 3: collect candidates >= threshold. Blocks whose chunk max < thr
// exit after two scalar loads (~99.6% of blocks).
// Key = (valbits << 32) | ~flatidx: descending value, then ascending index —
// exactly lax.top_k / numpy tie-break order.
// ---------------------------------------------------------------------------
__global__ __launch_bounds__(256) void k_collect(
    const float* __restrict__ sp, const float* __restrict__ pp,
    const float* __restrict__ cmax, const float* __restrict__ thr,
    int* __restrict__ cnt, unsigned long long* __restrict__ cand, int cap)
{
    int c   = blockIdx.x;
    int row = c / NCHUNK;
    float tval = thr[row];
    if (cmax[c] < tval) return;

    int cr = c - row * NCHUNK;
    long base = (long)row * ROW + (long)cr * CHUNK;
    int fr    = cr * CHUNK;
    int leaf0 = fr / VOCAB;
    int bnd   = (leaf0 + 1) * VOCAB;
    float p0  = pp[row * NLEAF + leaf0];
    float p1  = (leaf0 + 1 < NLEAF) ? pp[row * NLEAF + leaf0 + 1] : 0.f;

    int t = threadIdx.x;
    const float4* sp4 = (const float4*)(sp + base);
#pragma unroll
    for (int i = 0; i < 4; ++i) {
        int e4 = t + i * 256;
        float4 v = sp4[e4];
        int f = fr + e4 * 4;
        float p = (f < bnd) ? p0 : p1;
        float vv[4] = { v.x * p, v.y * p, v.z * p, v.w * p };
#pragma unroll
        for (int j = 0; j < 4; ++j) {
            if (vv[j] >= tval) {
                int pos = atomicAdd(&cnt[row], 1);
                if (pos < cap) {
                    unsigned int fb = __float_as_uint(vv[j]);
                    unsigned int fi = (unsigned int)(f + j);
                    cand[(long)row * cap + pos] =
                        ((unsigned long long)fb << 32) |
                        (unsigned long long)(0xFFFFFFFFu - fi);
                }
            }
        }
    }
}

// ---------------------------------------------------------------------------
// Kernel 4: per row, 64 iterations of block argmax over candidates; decode
// and write outputs: [token_ids | topk_probs | parent_indices], each [B,K],
// all as float32 (harness reads the concatenated buffer as float32).
// ---------------------------------------------------------------------------
__global__ __launch_bounds__(256) void k_final(
    const int* __restrict__ cnt, unsigned long long* __restrict__ cand,
    int cap, float* __restrict__ out)
{
    int row = blockIdx.x;
    int nc  = cnt[row]; if (nc > cap) nc = cap;
    unsigned long long* c = cand + (long)row * cap;
    __shared__ unsigned long long skey[256];
    __shared__ int spos[256];
    int t = threadIdx.x;

    for (int it = 0; it < TOPK; ++it) {
        unsigned long long lk = 0; int lp = -1;
        for (int i = t; i < nc; i += 256) {
            unsigned long long k = c[i];
            if (k > lk) { lk = k; lp = i; }
        }
        skey[t] = lk; spos[t] = lp;
        __syncthreads();
        for (int off = 128; off; off >>= 1) {
            if (t < off && skey[t + off] > skey[t]) {
                skey[t] = skey[t + off]; spos[t] = spos[t + off];
            }
            __syncthreads();
        }
        if (t == 0) {
            unsigned long long k = skey[0];
            float val = 0.f; unsigned int fi = 0;
            if (spos[0] >= 0 && k != 0ull) {
                val = __uint_as_float((unsigned int)(k >> 32));
                fi  = 0xFFFFFFFFu - (unsigned int)(k & 0xFFFFFFFFull);
                c[spos[0]] = 0ull;   // consume
            }
            int tok  = (int)(fi % VOCAB);
            int leaf = (int)(fi / VOCAB);
            out[row * TOPK + it]                     = (float)tok;
            out[BATCH * TOPK + row * TOPK + it]      = val;
            out[2 * BATCH * TOPK + row * TOPK + it]  = (float)leaf;
        }
        __syncthreads();
    }
}

extern "C" void kernel_launch(void* const* d_in, const int* in_sizes, int n_in,
                              void* d_out, int out_size, void* d_ws, size_t ws_size,
                              hipStream_t stream) {
    const float* sp = (const float*)d_in[0];   // [8,64,128000] f32
    const float* pp = (const float*)d_in[1];   // [8,64] f32
    float* out = (float*)d_out;                // 1536 f32

    char* ws = (char*)d_ws;
    float* cmax = (float*)ws;                              // 16000 f32 = 64000 B
    float* thr  = (float*)(ws + 64000);                    // 8 f32
    int*   cnt  = (int*)(ws + 64032);                      // 8 i32
    unsigned long long* cand = (unsigned long long*)(ws + 65536);

    int cap = 16384;
    size_t need = 65536 + (size_t)BATCH * (size_t)cap * 8;
    if (ws_size < need) {
        cap = (int)((ws_size > 65536 ? (ws_size - 65536) : 0) / (BATCH * 8));
        if (cap < 256) cap = 256;  // minimal fallback
    }

    k_chunkmax <<<BATCH * NCHUNK, 256, 0, stream>>>(sp, pp, cmax);
    k_threshold<<<BATCH,          256, 0, stream>>>(cmax, thr, cnt);
    k_collect  <<<BATCH * NCHUNK, 256, 0, stream>>>(sp, pp, cmax, thr, cnt, cand, cap);
    k_final    <<<BATCH,          256, 0, stream>>>(cnt, cand, cap, out);
}

// Round 2
// 401.661 us; speedup vs baseline: 1.7420x; 1.7420x over previous
//
#include <hip/hip_runtime.h>
#include <stdint.h>

#define BATCH 8
#define NLEAF 64
#define VOCAB 128000
#define ROW (NLEAF * VOCAB)        // 8,192,000
#define CHUNK 4096
#define NCHUNK (ROW / CHUNK)       // 2000 (exact)
#define TOPK 64

// ---------------------------------------------------------------------------
// Kernel 1: per-chunk max of product. One block = one 4096-elem chunk.
// A chunk spans at most 2 leaves (CHUNK < VOCAB); VOCAB%4==0 so a float4
// never straddles a leaf boundary. This is the mandatory 262MB read.
// ---------------------------------------------------------------------------
__global__ __launch_bounds__(256) void k_chunkmax(
    const float* __restrict__ sp, const float* __restrict__ pp,
    float* __restrict__ cmax)
{
    int c   = blockIdx.x;            // 0 .. BATCH*NCHUNK-1
    int row = c / NCHUNK;
    int cr  = c - row * NCHUNK;
    long base = (long)row * ROW + (long)cr * CHUNK;
    int fr    = cr * CHUNK;          // row-local flat base
    int leaf0 = fr / VOCAB;
    int bnd   = (leaf0 + 1) * VOCAB; // row-local leaf boundary (multiple of 4)
    float p0  = pp[row * NLEAF + leaf0];
    float p1  = (leaf0 + 1 < NLEAF) ? pp[row * NLEAF + leaf0 + 1] : 0.f;

    int t = threadIdx.x;
    const float4* sp4 = (const float4*)(sp + base);
    float m = 0.f;                   // products are >= 0
#pragma unroll
    for (int i = 0; i < 4; ++i) {
        int e4 = t + i * 256;        // float4 index within chunk
        float4 v = sp4[e4];
        float p = ((fr + e4 * 4) < bnd) ? p0 : p1;
        m = fmaxf(m, fmaxf(fmaxf(v.x * p, v.y * p), fmaxf(v.z * p, v.w * p)));
    }
    for (int off = 32; off; off >>= 1) m = fmaxf(m, __shfl_down(m, off, 64));
    __shared__ float s[4];
    if ((t & 63) == 0) s[t >> 6] = m;
    __syncthreads();
    if (t == 0) cmax[c] = fmaxf(fmaxf(s[0], s[1]), fmaxf(s[2], s[3]));
}

// ---------------------------------------------------------------------------
// Kernel 2: per row, EXACT 64th-largest chunk max via 4-level radix select
// on the float bits (values >= 0 so uint order == float order).
// Also zeroes the candidate counter.
// ---------------------------------------------------------------------------
__global__ __launch_bounds__(256) void k_threshold(
    const float* __restrict__ cmax, float* __restrict__ thr,
    int* __restrict__ cnt)
{
    int row = blockIdx.x;
    int t = threadIdx.x;
    __shared__ unsigned uv[NCHUNK];
    __shared__ int hist[256], sc[256];
    __shared__ unsigned s_prefix;
    __shared__ int s_k;
    for (int i = t; i < NCHUNK; i += 256)
        uv[i] = __float_as_uint(cmax[row * NCHUNK + i]);
    if (t == 0) { cnt[row] = 0; s_prefix = 0u; s_k = TOPK; }
    __syncthreads();

    for (int level = 3; level >= 0; --level) {
        int shift = level * 8;
        hist[t] = 0;
        __syncthreads();
        unsigned prefix = s_prefix; int kk = s_k;
        for (int i = t; i < NCHUNK; i += 256) {
            unsigned u = uv[i];
            bool mm = (level == 3) || ((u >> (shift + 8)) == prefix);
            unsigned bin = mm ? ((u >> shift) & 255u) : 0xFFFFFFFFu;
            // wave-uniform fast path (degenerate levels: all keys same byte)
            unsigned fb = __builtin_amdgcn_readfirstlane(bin);
            unsigned long long bal = __ballot(bin == fb);
            if (bal == ~0ull) {
                if ((t & 63) == 0 && fb != 0xFFFFFFFFu) atomicAdd(&hist[fb], 64);
            } else if (bin != 0xFFFFFFFFu) {
                atomicAdd(&hist[bin], 1);
            }
        }
        __syncthreads();
        sc[t] = hist[t];
        __syncthreads();
        for (int off = 1; off < 256; off <<= 1) {
            int v = sc[t];
            if (t + off < 256) v += sc[t + off];
            __syncthreads();
            sc[t] = v;
            __syncthreads();
        }
        int gt = (t < 255) ? sc[t + 1] : 0;   // count of keys strictly above bin t
        if (gt < kk && kk <= gt + hist[t]) {
            s_prefix = (prefix << 8) | (unsigned)t;
            s_k = kk - gt;
        }
        __syncthreads();
    }
    if (t == 0) thr[row] = __uint_as_float(s_prefix);
}

// ---------------------------------------------------------------------------
// Kernel 3: collect candidates >= threshold with ONE atomic per block
// (block prefix-sum over per-thread match counts). ~99.4% of blocks exit
// after two scalar loads.
// ---------------------------------------------------------------------------
__global__ __launch_bounds__(256) void k_collect(
    const float* __restrict__ sp, const float* __restrict__ pp,
    const float* __restrict__ cmax, const float* __restrict__ thr,
    int* __restrict__ cnt, unsigned long long* __restrict__ cand, int cap)
{
    int c   = blockIdx.x;
    int row = c / NCHUNK;
    float tval = thr[row];
    if (cmax[c] < tval) return;   // block-uniform exit

    int cr = c - row * NCHUNK;
    long base = (long)row * ROW + (long)cr * CHUNK;
    int fr    = cr * CHUNK;
    int leaf0 = fr / VOCAB;
    int bnd   = (leaf0 + 1) * VOCAB;
    float p0  = pp[row * NLEAF + leaf0];
    float p1  = (leaf0 + 1 < NLEAF) ? pp[row * NLEAF + leaf0 + 1] : 0.f;

    int t = threadIdx.x;
    const float4* sp4 = (const float4*)(sp + base);
    float pr[16];
    int m = 0;
#pragma unroll
    for (int i = 0; i < 4; ++i) {
        int e4 = t + i * 256;
        float4 v = sp4[e4];
        float p = ((fr + e4 * 4) < bnd) ? p0 : p1;
        pr[i * 4 + 0] = v.x * p;
        pr[i * 4 + 1] = v.y * p;
        pr[i * 4 + 2] = v.z * p;
        pr[i * 4 + 3] = v.w * p;
#pragma unroll
        for (int j = 0; j < 4; ++j) m += (pr[i * 4 + j] >= tval) ? 1 : 0;
    }

    __shared__ int sc2[256];
    __shared__ int sbase;
    sc2[t] = m;
    __syncthreads();
    for (int off = 1; off < 256; off <<= 1) {       // inclusive Hillis-Steele
        int v = sc2[t];
        if (t >= off) v += sc2[t - off];
        __syncthreads();
        sc2[t] = v;
        __syncthreads();
    }
    if (t == 255) sbase = atomicAdd(&cnt[row], sc2[255]);
    __syncthreads();

    if (m > 0) {
        int pos = sbase + sc2[t] - m;
#pragma unroll
        for (int i = 0; i < 4; ++i) {
#pragma unroll
            for (int j = 0; j < 4; ++j) {
                float v = pr[i * 4 + j];
                if (v >= tval) {
                    if (pos < cap) {
                        unsigned fb = __float_as_uint(v);
                        unsigned fi = (unsigned)(fr + (t + i * 256) * 4 + j);
                        cand[(long)row * cap + pos] =
                            ((unsigned long long)fb << 32) |
                            (unsigned long long)(0xFFFFFFFFu - fi);
                    }
                    pos++;
                }
            }
        }
    }
}

// ---------------------------------------------------------------------------
// Kernel 4: per row, exact 64th-largest 64-bit key via 8-level radix select
// (keys unique -> exactly 64 keys >= K64), compact, rank-sort, write outputs
// [token_ids | topk_probs | parent_indices] as float32.
// ---------------------------------------------------------------------------
__global__ __launch_bounds__(256) void k_final(
    const int* __restrict__ cnt, const unsigned long long* __restrict__ cand,
    int cap, float* __restrict__ out)
{
    int row = blockIdx.x;
    int t = threadIdx.x;
    int nc = cnt[row]; if (nc > cap) nc = cap;
    const unsigned long long* c = cand + (long)row * cap;

    __shared__ int hist[256], sc[256];
    __shared__ unsigned long long s_prefix;
    __shared__ int s_k;
    __shared__ unsigned long long stop[TOPK];
    __shared__ int s_ntop;
    if (t == 0) { s_prefix = 0ull; s_k = TOPK; s_ntop = 0; }
    __syncthreads();

    for (int level = 7; level >= 0; --level) {
        int shift = level * 8;
        hist[t] = 0;
        __syncthreads();
        unsigned long long prefix = s_prefix; int kk = s_k;
        for (int i = t; i < nc; i += 256) {
            unsigned long long u = c[i];
            bool mm = (level == 7) || ((u >> (shift + 8)) == prefix);
            unsigned bin = mm ? (unsigned)((u >> shift) & 255ull) : 0xFFFFFFFFu;
            unsigned fb = __builtin_amdgcn_readfirstlane(bin);
            unsigned long long bal = __ballot(bin == fb);
            if (bal == ~0ull) {
                if ((t & 63) == 0 && fb != 0xFFFFFFFFu) atomicAdd(&hist[fb], 64);
            } else if (bin != 0xFFFFFFFFu) {
                atomicAdd(&hist[bin], 1);
            }
        }
        __syncthreads();
        sc[t] = hist[t];
        __syncthreads();
        for (int off = 1; off < 256; off <<= 1) {
            int v = sc[t];
            if (t + off < 256) v += sc[t + off];
            __syncthreads();
            sc[t] = v;
            __syncthreads();
        }
        int gt = (t < 255) ? sc[t + 1] : 0;
        if (gt < kk && kk <= gt + hist[t]) {
            s_prefix = (prefix << 8) | (unsigned long long)t;
            s_k = kk - gt;
        }
        __syncthreads();
    }

    unsigned long long K64 = s_prefix;   // exact 64th-largest key
    for (int i = t; i < nc; i += 256) {
        unsigned long long u = c[i];
        if (u >= K64) {
            int p = atomicAdd(&s_ntop, 1);
            if (p < TOPK) stop[p] = u;
        }
    }
    __syncthreads();

    int ntop = s_ntop; if (ntop > TOPK) ntop = TOPK;
    if (t < ntop) {
        unsigned long long mykey = stop[t];
        int rank = 0;
        for (int j = 0; j < ntop; ++j) rank += (stop[j] > mykey) ? 1 : 0;
        unsigned fi = 0xFFFFFFFFu - (unsigned)(mykey & 0xFFFFFFFFull);
        float val = __uint_as_float((unsigned)(mykey >> 32));
        int tok  = (int)(fi % VOCAB);
        int leaf = (int)(fi / VOCAB);
        out[row * TOPK + rank]                    = (float)tok;
        out[BATCH * TOPK + row * TOPK + rank]     = val;
        out[2 * BATCH * TOPK + row * TOPK + rank] = (float)leaf;
    }
}

extern "C" void kernel_launch(void* const* d_in, const int* in_sizes, int n_in,
                              void* d_out, int out_size, void* d_ws, size_t ws_size,
                              hipStream_t stream) {
    const float* sp = (const float*)d_in[0];   // [8,64,128000] f32
    const float* pp = (const float*)d_in[1];   // [8,64] f32
    float* out = (float*)d_out;                // 1536 f32

    char* ws = (char*)d_ws;
    float* cmax = (float*)ws;                              // 16000 f32
    float* thr  = (float*)(ws + 64000);                    // 8 f32
    int*   cnt  = (int*)(ws + 64032);                      // 8 i32
    unsigned long long* cand = (unsigned long long*)(ws + 65536);

    int cap = 16384;
    size_t need = 65536 + (size_t)BATCH * (size_t)cap * 8;
    if (ws_size < need) {
        cap = (int)((ws_size > 65536 ? (ws_size - 65536) : 0) / (BATCH * 8));
        if (cap < 256) cap = 256;
    }

    k_chunkmax <<<BATCH * NCHUNK, 256, 0, stream>>>(sp, pp, cmax);
    k_threshold<<<BATCH,          256, 0, stream>>>(cmax, thr, cnt);
    k_collect  <<<BATCH * NCHUNK, 256, 0, stream>>>(sp, pp, cmax, thr, cnt, cand, cap);
    k_final    <<<BATCH,          256, 0, stream>>>(cnt, cand, cap, out);
}